// Round 1
// baseline (600.597 us; speedup 1.0000x reference)
//
#include <hip/hip_runtime.h>
#include <cstdint>
#include <cstddef>

// Problem constants (B=8, N=4096, C=512, H=2048, WIN=32, SHIFT=16, nW=128)
//   rows  = B*N = 32768
// ws layout (bytes):
//   kv_out f32 : [0,          67108864)
//   hn     bf16: [67108864,   100663296)
//   Y1     bf16: [100663296,  234881024)
//   w1b    bf16: [234881024,  236978176)
//   w2b    bf16: [236978176,  239075328)   total ~239 MB

typedef __attribute__((ext_vector_type(4))) float f32x4;
typedef __attribute__((ext_vector_type(8))) __bf16 bf16x8;
typedef __attribute__((ext_vector_type(8))) unsigned short us8;
typedef __attribute__((ext_vector_type(4))) unsigned short us4;

__device__ __forceinline__ unsigned short f2bf(float f) {
  unsigned int u = __builtin_bit_cast(unsigned int, f);
  u += 0x7fffu + ((u >> 16) & 1u);
  return (unsigned short)(u >> 16);
}

#define GLDS16(g, l)                                                         \
  __builtin_amdgcn_global_load_lds(                                          \
      (const __attribute__((address_space(1))) void*)(g),                    \
      (__attribute__((address_space(3))) void*)(l), 16, 0, 0)

// ---------------------------------------------------------------------------
// Kernel 0: convert fc1_w / fc2_w (each 1048576 f32) to bf16
// ---------------------------------------------------------------------------
__global__ __launch_bounds__(256) void wconv_kernel(
    const float* __restrict__ w1, const float* __restrict__ w2,
    unsigned short* __restrict__ o1, unsigned short* __restrict__ o2) {
  const int i = (blockIdx.x * 256 + threadIdx.x) * 4;
  const float4 a = *(const float4*)(w1 + i);
  us4 pa;
  pa[0] = f2bf(a.x); pa[1] = f2bf(a.y); pa[2] = f2bf(a.z); pa[3] = f2bf(a.w);
  *(us4*)(o1 + i) = pa;
  const float4 b = *(const float4*)(w2 + i);
  us4 pb;
  pb[0] = f2bf(b.x); pb[1] = f2bf(b.y); pb[2] = f2bf(b.z); pb[3] = f2bf(b.w);
  *(us4*)(o2 + i) = pb;
}

// ---------------------------------------------------------------------------
// Kernel 1: fused LN1 + shift + window attention + scramble + residual + LN2
// One block (256 thr) per window; 1024 windows.
// Row r of window (b,wi) <-> global n = (wi*32 + r + 16) & 4095 (both in & out)
// ---------------------------------------------------------------------------
__global__ __launch_bounds__(256) void attn_kernel(
    const float* __restrict__ qg, const float* __restrict__ kvg,
    const float* __restrict__ maskg,
    const float* __restrict__ n1w, const float* __restrict__ n1b,
    const float* __restrict__ n2w, const float* __restrict__ n2b,
    float* __restrict__ kv_out, unsigned short* __restrict__ hn) {
  // qn [32][516] f32 | kn [32][516] f32 | S [32][36] f32 ; xb aliases qn
  __shared__ __align__(16) float sm[2 * 32 * 516 + 32 * 36];
  float* qn = sm;
  float* kn = sm + 32 * 516;
  float* S  = sm + 2 * 32 * 516;
  float* xb = sm;  // alias of qn (dead after scores)

  const int t  = threadIdx.x;
  const int g  = blockIdx.x;
  const int b  = g >> 7;
  const int wi = g & 127;
  const int rg = t >> 3;   // row 0..31
  const int lk = t & 7;    // 8 threads per row

  const int n = (wi * 32 + rg + 16) & 4095;
  const float* qrow = qg  + ((size_t)b * 4096 + n) * 512;
  const float* krow = kvg + ((size_t)b * 4096 + n) * 512;

  // ---- phase 1: load + LN1 both streams into LDS (f32) ----
  float sq = 0.f, s2q = 0.f, sk = 0.f, s2k = 0.f;
#pragma unroll
  for (int j = 0; j < 16; ++j) {
    const int c = lk * 64 + j * 4;
    const float4 a = *(const float4*)(qrow + c);
    const float4 v = *(const float4*)(krow + c);
    *(float4*)(qn + rg * 516 + c) = a;
    *(float4*)(kn + rg * 516 + c) = v;
    sq  += a.x + a.y + a.z + a.w;
    s2q += a.x * a.x + a.y * a.y + a.z * a.z + a.w * a.w;
    sk  += v.x + v.y + v.z + v.w;
    s2k += v.x * v.x + v.y * v.y + v.z * v.z + v.w * v.w;
  }
#pragma unroll
  for (int m = 1; m < 8; m <<= 1) {
    sq += __shfl_xor(sq, m);  s2q += __shfl_xor(s2q, m);
    sk += __shfl_xor(sk, m);  s2k += __shfl_xor(s2k, m);
  }
  const float muq = sq * (1.f / 512.f);
  const float rsq = rsqrtf(s2q * (1.f / 512.f) - muq * muq + 1e-5f);
  const float muk = sk * (1.f / 512.f);
  const float rsk = rsqrtf(s2k * (1.f / 512.f) - muk * muk + 1e-5f);
#pragma unroll
  for (int j = 0; j < 16; ++j) {
    const int c = lk * 64 + j * 4;
    const float4 w4 = *(const float4*)(n1w + c);
    const float4 b4 = *(const float4*)(n1b + c);
    float4 a = *(const float4*)(qn + rg * 516 + c);
    float4 v = *(const float4*)(kn + rg * 516 + c);
    a.x = (a.x - muq) * rsq * w4.x + b4.x;
    a.y = (a.y - muq) * rsq * w4.y + b4.y;
    a.z = (a.z - muq) * rsq * w4.z + b4.z;
    a.w = (a.w - muq) * rsq * w4.w + b4.w;
    v.x = (v.x - muk) * rsk * w4.x + b4.x;
    v.y = (v.y - muk) * rsk * w4.y + b4.y;
    v.z = (v.z - muk) * rsk * w4.z + b4.z;
    v.w = (v.w - muk) * rsk * w4.w + b4.w;
    *(float4*)(qn + rg * 516 + c) = a;
    *(float4*)(kn + rg * 516 + c) = v;
  }
  __syncthreads();

  // ---- phase 2+3: scores (4 j's per thread) + mask + softmax ----
  {
    float a0 = 0.f, a1 = 0.f, a2 = 0.f, a3 = 0.f;
    const float* qr = qn + rg * 516;
    const float* k0 = kn + (lk + 0)  * 516;
    const float* k1 = kn + (lk + 8)  * 516;
    const float* k2 = kn + (lk + 16) * 516;
    const float* k3 = kn + (lk + 24) * 516;
#pragma unroll 4
    for (int c = 0; c < 512; c += 4) {
      const float4 a  = *(const float4*)(qr + c);
      const float4 x0 = *(const float4*)(k0 + c);
      const float4 x1 = *(const float4*)(k1 + c);
      const float4 x2 = *(const float4*)(k2 + c);
      const float4 x3 = *(const float4*)(k3 + c);
      a0 += a.x * x0.x + a.y * x0.y + a.z * x0.z + a.w * x0.w;
      a1 += a.x * x1.x + a.y * x1.y + a.z * x1.z + a.w * x1.w;
      a2 += a.x * x2.x + a.y * x2.y + a.z * x2.z + a.w * x2.w;
      a3 += a.x * x3.x + a.y * x3.y + a.z * x3.z + a.w * x3.w;
    }
    const float* mrow = maskg + (size_t)wi * 1024 + rg * 32;
    a0 += mrow[lk];      a1 += mrow[lk + 8];
    a2 += mrow[lk + 16]; a3 += mrow[lk + 24];
    float mx = fmaxf(fmaxf(a0, a1), fmaxf(a2, a3));
#pragma unroll
    for (int m = 1; m < 8; m <<= 1) mx = fmaxf(mx, __shfl_xor(mx, m));
    const float e0 = expf(a0 - mx), e1 = expf(a1 - mx);
    const float e2 = expf(a2 - mx), e3 = expf(a3 - mx);
    float sum = e0 + e1 + e2 + e3;
#pragma unroll
    for (int m = 1; m < 8; m <<= 1) sum += __shfl_xor(sum, m);
    const float inv = 1.f / sum;
    S[rg * 36 + lk]      = e0 * inv;
    S[rg * 36 + lk + 8]  = e1 * inv;
    S[rg * 36 + lk + 16] = e2 * inv;
    S[rg * 36 + lk + 24] = e3 * inv;
  }
  __syncthreads();

  // ---- phase 4: x = P @ kn  -> xb (aliases qn) ----
  {
    float pr[32];
#pragma unroll
    for (int j4 = 0; j4 < 8; ++j4) {
      const float4 v = *(const float4*)(S + rg * 36 + j4 * 4);
      pr[j4 * 4 + 0] = v.x; pr[j4 * 4 + 1] = v.y;
      pr[j4 * 4 + 2] = v.z; pr[j4 * 4 + 3] = v.w;
    }
#pragma unroll
    for (int cc = 0; cc < 16; ++cc) {
      const int c = lk * 64 + (((cc + lk) & 15) << 2);  // staggered, bank-clean
      float4 acc = {0.f, 0.f, 0.f, 0.f};
#pragma unroll
      for (int j = 0; j < 32; ++j) {
        const float4 kx = *(const float4*)(kn + j * 516 + c);
        acc.x += pr[j] * kx.x; acc.y += pr[j] * kx.y;
        acc.z += pr[j] * kx.z; acc.w += pr[j] * kx.w;
      }
      *(float4*)(xb + rg * 516 + c) = acc;
    }
  }
  __syncthreads();

  // ---- phase 5: scramble out[p][q] = x[q%32][p*16+q/32]; +kv; LN2 -> hn ----
  {
    float* orow = kv_out + ((size_t)b * 4096 + n) * 512;
    unsigned short* hrow = hn + ((size_t)b * 4096 + n) * 512;
    float4 vals[16];
    float s = 0.f, s2 = 0.f;
#pragma unroll
    for (int j = 0; j < 16; ++j) {
      const int qq = lk * 64 + j * 4;
      float4 r = *(const float4*)(krow + qq);  // shortcut = kv (L1-hot)
      const int cb = rg * 16 + (qq >> 5);
      const int ib = qq & 31;
      r.x += xb[(ib + 0) * 516 + cb];
      r.y += xb[(ib + 1) * 516 + cb];
      r.z += xb[(ib + 2) * 516 + cb];
      r.w += xb[(ib + 3) * 516 + cb];
      vals[j] = r;
      *(float4*)(orow + qq) = r;
      s  += r.x + r.y + r.z + r.w;
      s2 += r.x * r.x + r.y * r.y + r.z * r.z + r.w * r.w;
    }
#pragma unroll
    for (int m = 1; m < 8; m <<= 1) {
      s += __shfl_xor(s, m); s2 += __shfl_xor(s2, m);
    }
    const float mu   = s * (1.f / 512.f);
    const float rstd = rsqrtf(s2 * (1.f / 512.f) - mu * mu + 1e-5f);
#pragma unroll
    for (int j = 0; j < 16; ++j) {
      const int qq = lk * 64 + j * 4;
      const float4 w4 = *(const float4*)(n2w + qq);
      const float4 b4 = *(const float4*)(n2b + qq);
      const float4 r = vals[j];
      us4 h;
      h[0] = f2bf((r.x - mu) * rstd * w4.x + b4.x);
      h[1] = f2bf((r.y - mu) * rstd * w4.y + b4.y);
      h[2] = f2bf((r.z - mu) * rstd * w4.z + b4.z);
      h[3] = f2bf((r.w - mu) * rstd * w4.w + b4.w);
      *(us4*)(hrow + qq) = h;
    }
  }
}

// ---------------------------------------------------------------------------
// Kernel 2: Y1 = gelu(hn @ w1b^T + b1)   M=32768 N=2048 K=512  (bf16 MFMA)
// m97 structure: 128x128 tile, BK=32, global_load_lds(16B), 4 waves 2x2
// ---------------------------------------------------------------------------
__global__ __launch_bounds__(256) void gemm1_kernel(
    const unsigned short* __restrict__ A, const unsigned short* __restrict__ Bw,
    const float* __restrict__ bias, unsigned short* __restrict__ Y) {
  __shared__ __align__(16) char smem[32768];
  unsigned short* As = (unsigned short*)smem;            // [128][32]
  unsigned short* Bs = (unsigned short*)(smem + 8192);   // [128][32]

  const int tid = threadIdx.x;
  const int m0 = blockIdx.x << 7;
  const int n0 = blockIdx.y << 7;
  const int l  = tid & 63;
  const int wv = tid >> 6;
  const int wr = wv >> 1, wc = wv & 1;
  const int srow = tid >> 2;            // staging row 0..63
  const int scol = (tid & 3) << 3;      // staging col {0,8,16,24}
  const int lrow = l & 15;
  const int lko  = (l >> 4) << 3;

  f32x4 acc[4][4] = {};

  const unsigned short* pA = A  + (size_t)(m0 + srow) * 512 + scol;
  const unsigned short* pB = Bw + (size_t)(n0 + srow) * 512 + scol;
  char* dA0 = smem + wv * 1024;
  char* dA1 = smem + 4096 + wv * 1024;
  char* dB0 = smem + 8192 + wv * 1024;
  char* dB1 = smem + 12288 + wv * 1024;

  for (int kt = 0; kt < 16; ++kt) {
    const int k0 = kt << 5;
    GLDS16(pA + k0, dA0);
    GLDS16(pA + 64 * 512 + k0, dA1);
    GLDS16(pB + k0, dB0);
    GLDS16(pB + 64 * 512 + k0, dB1);
    __syncthreads();
    bf16x8 af[4], bfr[4];
#pragma unroll
    for (int mi = 0; mi < 4; ++mi)
      af[mi] = *(const bf16x8*)(As + (wr * 64 + mi * 16 + lrow) * 32 + lko);
#pragma unroll
    for (int ni = 0; ni < 4; ++ni)
      bfr[ni] = *(const bf16x8*)(Bs + (wc * 64 + ni * 16 + lrow) * 32 + lko);
#pragma unroll
    for (int mi = 0; mi < 4; ++mi)
#pragma unroll
      for (int ni = 0; ni < 4; ++ni)
        acc[mi][ni] = __builtin_amdgcn_mfma_f32_16x16x32_bf16(
            af[mi], bfr[ni], acc[mi][ni], 0, 0, 0);
    __syncthreads();
  }

  float bn[4];
#pragma unroll
  for (int ni = 0; ni < 4; ++ni) bn[ni] = bias[n0 + wc * 64 + ni * 16 + (l & 15)];

  // epilogue: bias+gelu, XOR-swizzled LDS transpose, coalesced bf16 stores
  unsigned short* Ct = (unsigned short*)(smem + wv * 8192);  // [64][64]
#pragma unroll
  for (int mi = 0; mi < 4; ++mi)
#pragma unroll
    for (int ni = 0; ni < 4; ++ni)
#pragma unroll
      for (int r = 0; r < 4; ++r) {
        float v = acc[mi][ni][r] + bn[ni];
        v = 0.5f * v * (1.f + erff(v * 0.70710678118654752f));
        const int row  = mi * 16 + ((l >> 4) << 2) + r;
        const int colb = (((ni * 16 + (l & 15)) << 1)) ^ ((row & 7) << 4);
        *(unsigned short*)((char*)Ct + row * 128 + colb) = f2bf(v);
      }
  __syncthreads();
#pragma unroll
  for (int it = 0; it < 8; ++it) {
    const int row = it * 8 + (l >> 3);
    const int off = ((l & 7) << 4) ^ ((row & 7) << 4);
    const us8 v = *(const us8*)((char*)Ct + row * 128 + off);
    const int grow = m0 + wr * 64 + row;
    const int gcol = n0 + wc * 64 + ((l & 7) << 3);
    *(us8*)(Y + (size_t)grow * 2048 + gcol) = v;
  }
}

// ---------------------------------------------------------------------------
// Kernel 3: out = kv_out + (Y1 @ w2b^T + b2)  M=32768 N=512 K=2048 (bf16 MFMA)
// ---------------------------------------------------------------------------
__global__ __launch_bounds__(256) void gemm2_kernel(
    const unsigned short* __restrict__ A, const unsigned short* __restrict__ Bw,
    const float* __restrict__ bias, const float* __restrict__ res,
    float* __restrict__ out) {
  __shared__ __align__(16) char smem[65536];
  unsigned short* As = (unsigned short*)smem;
  unsigned short* Bs = (unsigned short*)(smem + 8192);

  const int tid = threadIdx.x;
  const int m0 = blockIdx.x << 7;
  const int n0 = blockIdx.y << 7;
  const int l  = tid & 63;
  const int wv = tid >> 6;
  const int wr = wv >> 1, wc = wv & 1;
  const int srow = tid >> 2;
  const int scol = (tid & 3) << 3;
  const int lrow = l & 15;
  const int lko  = (l >> 4) << 3;

  f32x4 acc[4][4] = {};

  const unsigned short* pA = A  + (size_t)(m0 + srow) * 2048 + scol;
  const unsigned short* pB = Bw + (size_t)(n0 + srow) * 2048 + scol;
  char* dA0 = smem + wv * 1024;
  char* dA1 = smem + 4096 + wv * 1024;
  char* dB0 = smem + 8192 + wv * 1024;
  char* dB1 = smem + 12288 + wv * 1024;

  for (int kt = 0; kt < 64; ++kt) {
    const int k0 = kt << 5;
    GLDS16(pA + k0, dA0);
    GLDS16(pA + 64 * 2048 + k0, dA1);
    GLDS16(pB + k0, dB0);
    GLDS16(pB + 64 * 2048 + k0, dB1);
    __syncthreads();
    bf16x8 af[4], bfr[4];
#pragma unroll
    for (int mi = 0; mi < 4; ++mi)
      af[mi] = *(const bf16x8*)(As + (wr * 64 + mi * 16 + lrow) * 32 + lko);
#pragma unroll
    for (int ni = 0; ni < 4; ++ni)
      bfr[ni] = *(const bf16x8*)(Bs + (wc * 64 + ni * 16 + lrow) * 32 + lko);
#pragma unroll
    for (int mi = 0; mi < 4; ++mi)
#pragma unroll
      for (int ni = 0; ni < 4; ++ni)
        acc[mi][ni] = __builtin_amdgcn_mfma_f32_16x16x32_bf16(
            af[mi], bfr[ni], acc[mi][ni], 0, 0, 0);
    __syncthreads();
  }

  // epilogue: f32 XOR-swizzled LDS transpose, +bias +residual, float4 stores
  float* Ct = (float*)(smem + wv * 16384);  // [64][64] f32
#pragma unroll
  for (int mi = 0; mi < 4; ++mi)
#pragma unroll
    for (int ni = 0; ni < 4; ++ni)
#pragma unroll
      for (int r = 0; r < 4; ++r) {
        const int row  = mi * 16 + ((l >> 4) << 2) + r;
        const int col  = ni * 16 + (l & 15);
        const int colb = (col << 2) ^ ((row & 7) << 4);
        *(float*)((char*)Ct + (row << 8) + colb) = acc[mi][ni][r];
      }
  __syncthreads();
#pragma unroll
  for (int it = 0; it < 16; ++it) {
    const int row = it * 4 + (l >> 4);
    const int off = ((l & 15) << 4) ^ ((row & 7) << 4);
    f32x4 v = *(const f32x4*)((char*)Ct + (row << 8) + off);
    const int grow = m0 + wr * 64 + row;
    const int gcol = n0 + wc * 64 + ((l & 15) << 2);
    const f32x4 b4 = *(const f32x4*)(bias + gcol);
    const f32x4 r4 = *(const f32x4*)(res + (size_t)grow * 512 + gcol);
    v = v + b4 + r4;
    *(f32x4*)(out + (size_t)grow * 512 + gcol) = v;
  }
}

// ---------------------------------------------------------------------------
extern "C" void kernel_launch(void* const* d_in, const int* in_sizes, int n_in,
                              void* d_out, int out_size, void* d_ws,
                              size_t ws_size, hipStream_t stream) {
  const float* q   = (const float*)d_in[0];
  const float* kv  = (const float*)d_in[1];
  const float* msk = (const float*)d_in[2];
  const float* n1w = (const float*)d_in[3];
  const float* n1b = (const float*)d_in[4];
  const float* n2w = (const float*)d_in[5];
  const float* n2b = (const float*)d_in[6];
  const float* w1  = (const float*)d_in[7];
  const float* b1  = (const float*)d_in[8];
  const float* w2  = (const float*)d_in[9];
  const float* b2  = (const float*)d_in[10];
  float* out = (float*)d_out;

  char* ws = (char*)d_ws;
  float*          kv_out = (float*)ws;
  unsigned short* hn     = (unsigned short*)(ws + 67108864);
  unsigned short* Y1     = (unsigned short*)(ws + 100663296);
  unsigned short* w1b    = (unsigned short*)(ws + 234881024);
  unsigned short* w2b    = (unsigned short*)(ws + 236978176);

  hipLaunchKernelGGL(wconv_kernel, dim3(1024), dim3(256), 0, stream,
                     w1, w2, w1b, w2b);
  hipLaunchKernelGGL(attn_kernel, dim3(1024), dim3(256), 0, stream,
                     q, kv, msk, n1w, n1b, n2w, n2b, kv_out, hn);
  hipLaunchKernelGGL(gemm1_kernel, dim3(256, 16), dim3(256), 0, stream,
                     hn, w1b, b1, Y1);
  hipLaunchKernelGGL(gemm2_kernel, dim3(256, 4), dim3(256), 0, stream,
                     Y1, w2b, b2, kv_out, out);
}

// Round 2
// 509.593 us; speedup vs baseline: 1.1786x; 1.1786x over previous
//
#include <hip/hip_runtime.h>
#include <cstdint>
#include <cstddef>

// B=8, N=4096, C=512, H=2048, WIN=32, SHIFT=16, nW=128, rows=32768
// ws layout (bytes):
//   kv_out f32 : [0,          67108864)
//   hn     bf16: [67108864,   100663296)
//   Y1     bf16: [100663296,  234881024)
//   w1b    bf16: [234881024,  236978176)
//   w2b    bf16: [236978176,  239075328)
//   stats  f32 : [239075328,  239599616)  [32768][4] = muq,rsq,muk,rsk

typedef __attribute__((ext_vector_type(4)))  float f32x4;
typedef __attribute__((ext_vector_type(16))) float f32x16;
typedef __attribute__((ext_vector_type(8)))  __bf16 bf16x8;
typedef __attribute__((ext_vector_type(8)))  unsigned short us8;
typedef __attribute__((ext_vector_type(4)))  unsigned short us4;

__device__ __forceinline__ unsigned short f2bf(float f) {
  unsigned int u = __builtin_bit_cast(unsigned int, f);
  u += 0x7fffu + ((u >> 16) & 1u);
  return (unsigned short)(u >> 16);
}

#define GLDS16(g, l)                                                         \
  __builtin_amdgcn_global_load_lds(                                          \
      (const __attribute__((address_space(1))) void*)(g),                    \
      (__attribute__((address_space(3))) void*)(l), 16, 0, 0)

// ---------------------------------------------------------------------------
// Kernel 0: convert fc1_w / fc2_w to bf16
// ---------------------------------------------------------------------------
__global__ __launch_bounds__(256) void wconv_kernel(
    const float* __restrict__ w1, const float* __restrict__ w2,
    unsigned short* __restrict__ o1, unsigned short* __restrict__ o2) {
  const int i = (blockIdx.x * 256 + threadIdx.x) * 4;
  const f32x4 a = *(const f32x4*)(w1 + i);
  us4 pa; pa[0]=f2bf(a[0]); pa[1]=f2bf(a[1]); pa[2]=f2bf(a[2]); pa[3]=f2bf(a[3]);
  *(us4*)(o1 + i) = pa;
  const f32x4 b = *(const f32x4*)(w2 + i);
  us4 pb; pb[0]=f2bf(b[0]); pb[1]=f2bf(b[1]); pb[2]=f2bf(b[2]); pb[3]=f2bf(b[3]);
  *(us4*)(o2 + i) = pb;
}

// ---------------------------------------------------------------------------
// Kernel 1: LN1 row stats for q and kv.  wave per (row,stream).
// stats[row][4] = (muq, rsq, muk, rsk)
// ---------------------------------------------------------------------------
__global__ __launch_bounds__(256) void stats_kernel(
    const float* __restrict__ qg, const float* __restrict__ kvg,
    float* __restrict__ stats) {
  const int gw = (blockIdx.x * 256 + threadIdx.x) >> 6;  // 0..65535
  const int l  = threadIdx.x & 63;
  const int s  = gw & 1;
  const int row = gw >> 1;
  const float* src = (s ? kvg : qg) + (size_t)row * 512 + l * 8;
  const f32x4 v0 = *(const f32x4*)(src);
  const f32x4 v1 = *(const f32x4*)(src + 4);
  float a = 0.f, a2 = 0.f;
#pragma unroll
  for (int m = 0; m < 4; ++m) {
    a += v0[m] + v1[m];
    a2 += v0[m] * v0[m] + v1[m] * v1[m];
  }
#pragma unroll
  for (int mm = 1; mm <= 32; mm <<= 1) {
    a += __shfl_xor(a, mm); a2 += __shfl_xor(a2, mm);
  }
  if (l == 0) {
    const float mu = a * (1.f / 512.f);
    const float rs = rsqrtf(a2 * (1.f / 512.f) - mu * mu + 1e-5f);
    *(float2*)(stats + (size_t)row * 4 + s * 2) = make_float2(mu, rs);
  }
}

// ---------------------------------------------------------------------------
// Kernel 2: fused shifted-window attention, MFMA-based, LDS-free operands.
// Block = 128 thr = 2 waves = 1 window. Wave h covers K-half / N-half h.
//  QK^T: A=kn rows j (lane il), B=qn cols i (lane il); S accumulated with
//  bf16 hi/lo split (3 MFMA / 16-chunk) -> ~f32 accuracy.
//  D layout (32x32): row=(r&3)+8*(r>>2)+4*hi, col=il  [m74/m101]
//  LN1 folded out of PV: x[i][c] = w1[c]*(sum_j P[i][j]*rs_j*kv[j][c] + beta_i) + b1[c]
//  One PV n-tile (32 cols) = two complete scrambled output rows -> fused
//  residual + LN2 + hn write, no LDS.
// ---------------------------------------------------------------------------
__global__ __launch_bounds__(128) void attn2_kernel(
    const float* __restrict__ qg, const float* __restrict__ kvg,
    const float* __restrict__ maskg,
    const float* __restrict__ n1w, const float* __restrict__ n1b,
    const float* __restrict__ n2w, const float* __restrict__ n2b,
    const float* __restrict__ stats,
    float* __restrict__ kv_out, unsigned short* __restrict__ hn) {
  __shared__ __align__(16) float xch[2][4][64][4];  // 8 KB partial-S exchange

  const int t  = threadIdx.x;
  const int h  = t >> 6;       // K/N half
  const int l  = t & 63;
  const int il = l & 31;       // lane's window-row index (i for B, j for A)
  const int hi = l >> 5;
  const int g  = blockIdx.x;   // window 0..1023
  const int b  = g >> 7;
  const int wi = g & 127;
  const int wbase = wi * 32 + 16;

  const int nrow = (wbase + il) & 4095;
  const size_t rowidx = (size_t)b * 4096 + nrow;
  const float* qrow = qg  + rowidx * 512;
  const float* krow = kvg + rowidx * 512;
  const f32x4 st = *(const f32x4*)(stats + rowidx * 4);  // muq,rsq,muk,rsk

  // ---- QK^T over this wave's K-half ----
  f32x16 sacc = {};
#pragma unroll
  for (int t16 = 0; t16 < 16; ++t16) {
    const int kk = h * 256 + t16 * 16 + hi * 8;
    const f32x4 qa = *(const f32x4*)(qrow + kk);
    const f32x4 qb = *(const f32x4*)(qrow + kk + 4);
    const f32x4 ka = *(const f32x4*)(krow + kk);
    const f32x4 kb = *(const f32x4*)(krow + kk + 4);
    const f32x4 wa = *(const f32x4*)(n1w + kk);
    const f32x4 wb = *(const f32x4*)(n1w + kk + 4);
    const f32x4 ba = *(const f32x4*)(n1b + kk);
    const f32x4 bb = *(const f32x4*)(n1b + kk + 4);
    bf16x8 qh, ql, kh, kl;
#pragma unroll
    for (int e = 0; e < 8; ++e) {
      const float qe = (e < 4) ? qa[e] : qb[e - 4];
      const float ke = (e < 4) ? ka[e] : kb[e - 4];
      const float we = (e < 4) ? wa[e] : wb[e - 4];
      const float be = (e < 4) ? ba[e] : bb[e - 4];
      const float qn = (qe - st[0]) * st[1] * we + be;
      const float kn = (ke - st[2]) * st[3] * we + be;
      const __bf16 qhb = (__bf16)qn;
      const __bf16 khb = (__bf16)kn;
      qh[e] = qhb; ql[e] = (__bf16)(qn - (float)qhb);
      kh[e] = khb; kl[e] = (__bf16)(kn - (float)khb);
    }
    sacc = __builtin_amdgcn_mfma_f32_32x32x16_bf16(kh, qh, sacc, 0, 0, 0);
    sacc = __builtin_amdgcn_mfma_f32_32x32x16_bf16(kh, ql, sacc, 0, 0, 0);
    sacc = __builtin_amdgcn_mfma_f32_32x32x16_bf16(kl, qh, sacc, 0, 0, 0);
  }

  // ---- cross-wave partial-S exchange ----
#pragma unroll
  for (int qd = 0; qd < 4; ++qd) {
    f32x4 v = {sacc[qd*4+0], sacc[qd*4+1], sacc[qd*4+2], sacc[qd*4+3]};
    *(f32x4*)&xch[h][qd][l][0] = v;
  }
  __syncthreads();
  float sv[16];
#pragma unroll
  for (int qd = 0; qd < 4; ++qd) {
    const f32x4 v = *(const f32x4*)&xch[1 - h][qd][l][0];
#pragma unroll
    for (int m = 0; m < 4; ++m) sv[qd*4+m] = sacc[qd*4+m] + v[m];
  }

  // ---- mask + softmax (fully in-register; j lives in regs + partner lane) ----
  const float* mrow = maskg + (size_t)wi * 1024 + il * 32;
  float mx = -1e30f;
#pragma unroll
  for (int r = 0; r < 16; ++r) {
    const int j = (r & 3) + 8 * (r >> 2) + 4 * hi;
    sv[r] += mrow[j];
    mx = fmaxf(mx, sv[r]);
  }
  mx = fmaxf(mx, __shfl_xor(mx, 32));
  float P[16], sum = 0.f;
#pragma unroll
  for (int r = 0; r < 16; ++r) { P[r] = __expf(sv[r] - mx); sum += P[r]; }
  sum += __shfl_xor(sum, 32);
  const float inv = 1.f / sum;

  // ---- fold LN1(kv): P' = P*rs_j, beta_i = -sum_j P*mu_j*rs_j ----
  const float rs_own = st[3];
  const float ms_own = st[2] * st[3];
  float Pp[16], beta = 0.f;
#pragma unroll
  for (int r = 0; r < 16; ++r) {
    const int j = (r & 3) + 8 * (r >> 2) + 4 * hi;
    const float rsj = __shfl(rs_own, j);
    const float msj = __shfl(ms_own, j);
    P[r] *= inv;
    beta -= P[r] * msj;
    Pp[r] = P[r] * rsj;
  }
  beta += __shfl_xor(beta, 32);
  float breg[16];
#pragma unroll
  for (int r = 0; r < 16; ++r) {
    const int ir = (r & 3) + 8 * (r >> 2) + 4 * hi;
    breg[r] = __shfl(beta, ir);
  }

  // ---- P relayout to A-frag (lane keeps its i; swap j-halves via shfl) ----
  float Ps[16];
#pragma unroll
  for (int r = 0; r < 16; ++r) Ps[r] = __shfl_xor(Pp[r], 32);
  bf16x8 pa[2];
#pragma unroll
  for (int s = 0; s < 2; ++s) {
#pragma unroll
    for (int m = 0; m < 8; ++m) {
      float v;
      if (m < 4) v = (hi == 0) ? Pp[8*s+m] : Ps[8*s+m+4];
      else       v = (hi == 1) ? Pp[8*s+m] : Ps[8*s+m-4];
      pa[s][m] = (__bf16)v;
    }
  }

  // ---- PV + scramble + residual + LN2 + hn, per n-tile (2 out rows each) ----
  const size_t bbase = (size_t)b * 4096;
#pragma unroll 2
  for (int nt = 0; nt < 8; ++nt) {
    const int c = h * 256 + nt * 32 + il;
    const float* kvc = kvg + bbase * 512 + c;
    bf16x8 pb0, pb1;
#pragma unroll
    for (int e = 0; e < 8; ++e) {
      const int j0 = 8 * hi + e;
      const int r0 = (wbase + j0) & 4095;
      pb0[e] = (__bf16)kvc[(size_t)r0 * 512];
      const int r1 = (wbase + j0 + 16) & 4095;
      pb1[e] = (__bf16)kvc[(size_t)r1 * 512];
    }
    f32x16 x = {};
    x = __builtin_amdgcn_mfma_f32_32x32x16_bf16(pa[0], pb0, x, 0, 0, 0);
    x = __builtin_amdgcn_mfma_f32_32x32x16_bf16(pa[1], pb1, x, 0, 0, 0);

    const int p  = h * 16 + nt * 2 + (il >> 4);
    const int np = (wbase + p) & 4095;
    const size_t orow = (bbase + np) * 512;
    const float w1c = n1w[c], b1c = n1b[c];
    float ov[16], s1 = 0.f, s2 = 0.f;
#pragma unroll
    for (int qd = 0; qd < 4; ++qd) {
      const int q0 = (il & 15) * 32 + 8 * qd + 4 * hi;
      const f32x4 rv = *(const f32x4*)(kvg + orow + q0);
      f32x4 o;
#pragma unroll
      for (int m = 0; m < 4; ++m) {
        const int r = qd * 4 + m;
        const float xv = w1c * (x[r] + breg[r]) + b1c;
        o[m] = xv + rv[m];
        s1 += o[m]; s2 += o[m] * o[m];
        ov[r] = o[m];
      }
      *(f32x4*)(kv_out + orow + q0) = o;
    }
#pragma unroll
    for (int mm = 1; mm <= 8; mm <<= 1) {
      s1 += __shfl_xor(s1, mm); s2 += __shfl_xor(s2, mm);
    }
    s1 += __shfl_xor(s1, 32); s2 += __shfl_xor(s2, 32);
    const float mu2 = s1 * (1.f / 512.f);
    const float rr  = rsqrtf(s2 * (1.f / 512.f) - mu2 * mu2 + 1e-5f);
#pragma unroll
    for (int qd = 0; qd < 4; ++qd) {
      const int q0 = (il & 15) * 32 + 8 * qd + 4 * hi;
      const f32x4 w2v = *(const f32x4*)(n2w + q0);
      const f32x4 b2v = *(const f32x4*)(n2b + q0);
      us4 hh;
#pragma unroll
      for (int m = 0; m < 4; ++m)
        hh[m] = f2bf((ov[qd*4+m] - mu2) * rr * w2v[m] + b2v[m]);
      *(us4*)(hn + orow + q0) = hh;
    }
  }
}

// ---------------------------------------------------------------------------
// Kernel 3: Y1 = gelu(hn @ w1b^T + b1)  M=32768 N=2048 K=512
// 128x128 tile, BK=32, 2-phase double-buffered global_load_lds staging.
// ---------------------------------------------------------------------------
__global__ __launch_bounds__(256) void gemm1_kernel(
    const unsigned short* __restrict__ A, const unsigned short* __restrict__ Bw,
    const float* __restrict__ bias, unsigned short* __restrict__ Y) {
  __shared__ __align__(16) char smem[32768];  // 2 x (As 8K + Bs 8K)

  const int tid = threadIdx.x;
  const int m0 = blockIdx.x << 7;
  const int n0 = blockIdx.y << 7;
  const int l  = tid & 63;
  const int wv = tid >> 6;
  const int wr = wv >> 1, wc = wv & 1;
  const int srow = tid >> 2;
  const int scol = (tid & 3) << 3;
  const int lrow = l & 15;
  const int lko  = (l >> 4) << 3;

  f32x4 acc[4][4] = {};
  const unsigned short* pA = A  + (size_t)(m0 + srow) * 512 + scol;
  const unsigned short* pB = Bw + (size_t)(n0 + srow) * 512 + scol;

#define G1_STAGE(p, kt)                                                      \
  {                                                                          \
    char* base = smem + (p) * 16384;                                         \
    GLDS16(pA + (kt) * 32,            base + wv * 1024);                     \
    GLDS16(pA + 64 * 512 + (kt) * 32, base + 4096 + wv * 1024);              \
    GLDS16(pB + (kt) * 32,            base + 8192 + wv * 1024);              \
    GLDS16(pB + 64 * 512 + (kt) * 32, base + 12288 + wv * 1024);             \
  }

  G1_STAGE(0, 0);
  __syncthreads();
  for (int kt = 0; kt < 16; ++kt) {
    const int p = kt & 1;
    if (kt < 15) G1_STAGE(p ^ 1, kt + 1);
    const unsigned short* As = (const unsigned short*)(smem + p * 16384);
    const unsigned short* Bs = As + 4096;
    bf16x8 af[4], bfr[4];
#pragma unroll
    for (int mi = 0; mi < 4; ++mi)
      af[mi] = *(const bf16x8*)(As + (wr * 64 + mi * 16 + lrow) * 32 + lko);
#pragma unroll
    for (int ni = 0; ni < 4; ++ni)
      bfr[ni] = *(const bf16x8*)(Bs + (wc * 64 + ni * 16 + lrow) * 32 + lko);
#pragma unroll
    for (int mi = 0; mi < 4; ++mi)
#pragma unroll
      for (int ni = 0; ni < 4; ++ni)
        acc[mi][ni] = __builtin_amdgcn_mfma_f32_16x16x32_bf16(
            af[mi], bfr[ni], acc[mi][ni], 0, 0, 0);
    __syncthreads();
  }

  float bn[4];
#pragma unroll
  for (int ni = 0; ni < 4; ++ni) bn[ni] = bias[n0 + wc * 64 + ni * 16 + (l & 15)];

  // epilogue: bias+gelu, XOR-swizzled LDS transpose, coalesced bf16 stores
  unsigned short* Ct = (unsigned short*)(smem + wv * 8192);  // [64][64]
#pragma unroll
  for (int mi = 0; mi < 4; ++mi)
#pragma unroll
    for (int ni = 0; ni < 4; ++ni)
#pragma unroll
      for (int r = 0; r < 4; ++r) {
        float v = acc[mi][ni][r] + bn[ni];
        v = 0.5f * v * (1.f + erff(v * 0.70710678118654752f));
        const int row  = mi * 16 + ((l >> 4) << 2) + r;
        const int colb = (((ni * 16 + (l & 15)) << 1)) ^ ((row & 7) << 4);
        *(unsigned short*)((char*)Ct + row * 128 + colb) = f2bf(v);
      }
  __syncthreads();
#pragma unroll
  for (int it = 0; it < 8; ++it) {
    const int row = it * 8 + (l >> 3);
    const int off = ((l & 7) << 4) ^ ((row & 7) << 4);
    const us8 v = *(const us8*)((char*)Ct + row * 128 + off);
    const int grow = m0 + wr * 64 + row;
    const int gcol = n0 + wc * 64 + ((l & 7) << 3);
    *(us8*)(Y + (size_t)grow * 2048 + gcol) = v;
  }
}

// ---------------------------------------------------------------------------
// Kernel 4: out = kv_out + (Y1 @ w2b^T + b2)  M=32768 N=512 K=2048
// 2-phase double-buffered; direct (non-LDS) epilogue stores -> 32KB LDS.
// ---------------------------------------------------------------------------
__global__ __launch_bounds__(256) void gemm2_kernel(
    const unsigned short* __restrict__ A, const unsigned short* __restrict__ Bw,
    const float* __restrict__ bias, const float* __restrict__ res,
    float* __restrict__ out) {
  __shared__ __align__(16) char smem[32768];

  const int tid = threadIdx.x;
  const int m0 = blockIdx.x << 7;
  const int n0 = blockIdx.y << 7;
  const int l  = tid & 63;
  const int wv = tid >> 6;
  const int wr = wv >> 1, wc = wv & 1;
  const int srow = tid >> 2;
  const int scol = (tid & 3) << 3;
  const int lrow = l & 15;
  const int lko  = (l >> 4) << 3;

  f32x4 acc[4][4] = {};
  const unsigned short* pA = A  + (size_t)(m0 + srow) * 2048 + scol;
  const unsigned short* pB = Bw + (size_t)(n0 + srow) * 2048 + scol;

#define G2_STAGE(p, kt)                                                      \
  {                                                                          \
    char* base = smem + (p) * 16384;                                         \
    GLDS16(pA + (kt) * 32,             base + wv * 1024);                    \
    GLDS16(pA + 64 * 2048 + (kt) * 32, base + 4096 + wv * 1024);             \
    GLDS16(pB + (kt) * 32,             base + 8192 + wv * 1024);             \
    GLDS16(pB + 64 * 2048 + (kt) * 32, base + 12288 + wv * 1024);            \
  }

  G2_STAGE(0, 0);
  __syncthreads();
  for (int kt = 0; kt < 64; ++kt) {
    const int p = kt & 1;
    if (kt < 63) G2_STAGE(p ^ 1, kt + 1);
    const unsigned short* As = (const unsigned short*)(smem + p * 16384);
    const unsigned short* Bs = As + 4096;
    bf16x8 af[4], bfr[4];
#pragma unroll
    for (int mi = 0; mi < 4; ++mi)
      af[mi] = *(const bf16x8*)(As + (wr * 64 + mi * 16 + lrow) * 32 + lko);
#pragma unroll
    for (int ni = 0; ni < 4; ++ni)
      bfr[ni] = *(const bf16x8*)(Bs + (wc * 64 + ni * 16 + lrow) * 32 + lko);
#pragma unroll
    for (int mi = 0; mi < 4; ++mi)
#pragma unroll
      for (int ni = 0; ni < 4; ++ni)
        acc[mi][ni] = __builtin_amdgcn_mfma_f32_16x16x32_bf16(
            af[mi], bfr[ni], acc[mi][ni], 0, 0, 0);
    __syncthreads();
  }

  // direct epilogue: +bias +residual, scalar f32 stores (4x64B lines/instr)
#pragma unroll
  for (int ni = 0; ni < 4; ++ni) {
    const int col = n0 + wc * 64 + ni * 16 + (l & 15);
    const float bb = bias[col];
#pragma unroll
    for (int mi = 0; mi < 4; ++mi)
#pragma unroll
      for (int r = 0; r < 4; ++r) {
        const int row = m0 + wr * 64 + mi * 16 + ((l >> 4) << 2) + r;
        const size_t idx = (size_t)row * 512 + col;
        out[idx] = acc[mi][ni][r] + bb + res[idx];
      }
  }
}

// ---------------------------------------------------------------------------
extern "C" void kernel_launch(void* const* d_in, const int* in_sizes, int n_in,
                              void* d_out, int out_size, void* d_ws,
                              size_t ws_size, hipStream_t stream) {
  const float* q   = (const float*)d_in[0];
  const float* kv  = (const float*)d_in[1];
  const float* msk = (const float*)d_in[2];
  const float* n1w = (const float*)d_in[3];
  const float* n1b = (const float*)d_in[4];
  const float* n2w = (const float*)d_in[5];
  const float* n2b = (const float*)d_in[6];
  const float* w1  = (const float*)d_in[7];
  const float* b1  = (const float*)d_in[8];
  const float* w2  = (const float*)d_in[9];
  const float* b2  = (const float*)d_in[10];
  float* out = (float*)d_out;

  char* ws = (char*)d_ws;
  float*          kv_out = (float*)ws;
  unsigned short* hn     = (unsigned short*)(ws + 67108864);
  unsigned short* Y1     = (unsigned short*)(ws + 100663296);
  unsigned short* w1b    = (unsigned short*)(ws + 234881024);
  unsigned short* w2b    = (unsigned short*)(ws + 236978176);
  float*          stats  = (float*)(ws + 239075328);

  hipLaunchKernelGGL(wconv_kernel, dim3(1024), dim3(256), 0, stream,
                     w1, w2, w1b, w2b);
  hipLaunchKernelGGL(stats_kernel, dim3(16384), dim3(256), 0, stream,
                     q, kv, stats);
  hipLaunchKernelGGL(attn2_kernel, dim3(1024), dim3(128), 0, stream,
                     q, kv, msk, n1w, n1b, n2w, n2b, stats, kv_out, hn);
  hipLaunchKernelGGL(gemm1_kernel, dim3(256, 16), dim3(256), 0, stream,
                     hn, w1b, b1, Y1);
  hipLaunchKernelGGL(gemm2_kernel, dim3(256, 4), dim3(256), 0, stream,
                     Y1, w2b, b2, kv_out, out);
}

// Round 4
// 487.297 us; speedup vs baseline: 1.2325x; 1.0458x over previous
//
#include <hip/hip_runtime.h>
#include <cstdint>
#include <cstddef>

// B=8, N=4096, C=512, H=2048, WIN=32, SHIFT=16, nW=128, rows=32768
// ws layout (bytes):
//   kv_out f32 : [0,          67108864)
//   hn     bf16: [67108864,   100663296)
//   Y1     bf16: [100663296,  234881024)
//   w1b    bf16: [234881024,  236978176)
//   w2b    bf16: [236978176,  239075328)
//   stats  f32 : [239075328,  239599616)  [32768][4] = muq,rsq,muk,rsk

typedef __attribute__((ext_vector_type(4)))  float f32x4;
typedef __attribute__((ext_vector_type(16))) float f32x16;
typedef __attribute__((ext_vector_type(8)))  __bf16 bf16x8;
typedef __attribute__((ext_vector_type(8)))  unsigned short us8;
typedef __attribute__((ext_vector_type(4)))  unsigned short us4;

__device__ __forceinline__ unsigned short f2bf(float f) {
  unsigned int u = __builtin_bit_cast(unsigned int, f);
  u += 0x7fffu + ((u >> 16) & 1u);
  return (unsigned short)(u >> 16);
}

#define GLDS16(g, l)                                                         \
  __builtin_amdgcn_global_load_lds(                                          \
      (const __attribute__((address_space(1))) void*)(g),                    \
      (__attribute__((address_space(3))) void*)(l), 16, 0, 0)

#define BAR()                                                                \
  do {                                                                       \
    asm volatile("" ::: "memory");                                           \
    __builtin_amdgcn_s_barrier();                                            \
    asm volatile("" ::: "memory");                                           \
  } while (0)

#define VMW(n) asm volatile("s_waitcnt vmcnt(" #n ")" ::: "memory")

// ---------------------------------------------------------------------------
// Kernel 0: convert fc1_w / fc2_w to bf16
// ---------------------------------------------------------------------------
__global__ __launch_bounds__(256) void wconv_kernel(
    const float* __restrict__ w1, const float* __restrict__ w2,
    unsigned short* __restrict__ o1, unsigned short* __restrict__ o2) {
  const int i = (blockIdx.x * 256 + threadIdx.x) * 4;
  const f32x4 a = *(const f32x4*)(w1 + i);
  us4 pa; pa[0]=f2bf(a[0]); pa[1]=f2bf(a[1]); pa[2]=f2bf(a[2]); pa[3]=f2bf(a[3]);
  *(us4*)(o1 + i) = pa;
  const f32x4 b = *(const f32x4*)(w2 + i);
  us4 pb; pb[0]=f2bf(b[0]); pb[1]=f2bf(b[1]); pb[2]=f2bf(b[2]); pb[3]=f2bf(b[3]);
  *(us4*)(o2 + i) = pb;
}

// ---------------------------------------------------------------------------
// Kernel 1: LN1 row stats for q and kv
// ---------------------------------------------------------------------------
__global__ __launch_bounds__(256) void stats_kernel(
    const float* __restrict__ qg, const float* __restrict__ kvg,
    float* __restrict__ stats) {
  const int gw = (blockIdx.x * 256 + threadIdx.x) >> 6;
  const int l  = threadIdx.x & 63;
  const int s  = gw & 1;
  const int row = gw >> 1;
  const float* src = (s ? kvg : qg) + (size_t)row * 512 + l * 8;
  const f32x4 v0 = *(const f32x4*)(src);
  const f32x4 v1 = *(const f32x4*)(src + 4);
  float a = 0.f, a2 = 0.f;
#pragma unroll
  for (int m = 0; m < 4; ++m) {
    a += v0[m] + v1[m];
    a2 += v0[m] * v0[m] + v1[m] * v1[m];
  }
#pragma unroll
  for (int mm = 1; mm <= 32; mm <<= 1) {
    a += __shfl_xor(a, mm); a2 += __shfl_xor(a2, mm);
  }
  if (l == 0) {
    const float mu = a * (1.f / 512.f);
    const float rs = rsqrtf(a2 * (1.f / 512.f) - mu * mu + 1e-5f);
    *(float2*)(stats + (size_t)row * 4 + s * 2) = make_float2(mu, rs);
  }
}

// ---------------------------------------------------------------------------
// Kernel 2: fused shifted-window attention (unchanged from round 2)
// ---------------------------------------------------------------------------
__global__ __launch_bounds__(128) void attn2_kernel(
    const float* __restrict__ qg, const float* __restrict__ kvg,
    const float* __restrict__ maskg,
    const float* __restrict__ n1w, const float* __restrict__ n1b,
    const float* __restrict__ n2w, const float* __restrict__ n2b,
    const float* __restrict__ stats,
    float* __restrict__ kv_out, unsigned short* __restrict__ hn) {
  __shared__ __align__(16) float xch[2][4][64][4];

  const int t  = threadIdx.x;
  const int h  = t >> 6;
  const int l  = t & 63;
  const int il = l & 31;
  const int hi = l >> 5;
  const int g  = blockIdx.x;
  const int b  = g >> 7;
  const int wi = g & 127;
  const int wbase = wi * 32 + 16;

  const int nrow = (wbase + il) & 4095;
  const size_t rowidx = (size_t)b * 4096 + nrow;
  const float* qrow = qg  + rowidx * 512;
  const float* krow = kvg + rowidx * 512;
  const f32x4 st = *(const f32x4*)(stats + rowidx * 4);

  f32x16 sacc = {};
#pragma unroll
  for (int t16 = 0; t16 < 16; ++t16) {
    const int kk = h * 256 + t16 * 16 + hi * 8;
    const f32x4 qa = *(const f32x4*)(qrow + kk);
    const f32x4 qb = *(const f32x4*)(qrow + kk + 4);
    const f32x4 ka = *(const f32x4*)(krow + kk);
    const f32x4 kb = *(const f32x4*)(krow + kk + 4);
    const f32x4 wa = *(const f32x4*)(n1w + kk);
    const f32x4 wb = *(const f32x4*)(n1w + kk + 4);
    const f32x4 ba = *(const f32x4*)(n1b + kk);
    const f32x4 bb = *(const f32x4*)(n1b + kk + 4);
    bf16x8 qh, ql, kh, kl;
#pragma unroll
    for (int e = 0; e < 8; ++e) {
      const float qe = (e < 4) ? qa[e] : qb[e - 4];
      const float ke = (e < 4) ? ka[e] : kb[e - 4];
      const float we = (e < 4) ? wa[e] : wb[e - 4];
      const float be = (e < 4) ? ba[e] : bb[e - 4];
      const float qn = (qe - st[0]) * st[1] * we + be;
      const float kn = (ke - st[2]) * st[3] * we + be;
      const __bf16 qhb = (__bf16)qn;
      const __bf16 khb = (__bf16)kn;
      qh[e] = qhb; ql[e] = (__bf16)(qn - (float)qhb);
      kh[e] = khb; kl[e] = (__bf16)(kn - (float)khb);
    }
    sacc = __builtin_amdgcn_mfma_f32_32x32x16_bf16(kh, qh, sacc, 0, 0, 0);
    sacc = __builtin_amdgcn_mfma_f32_32x32x16_bf16(kh, ql, sacc, 0, 0, 0);
    sacc = __builtin_amdgcn_mfma_f32_32x32x16_bf16(kl, qh, sacc, 0, 0, 0);
  }

#pragma unroll
  for (int qd = 0; qd < 4; ++qd) {
    f32x4 v = {sacc[qd*4+0], sacc[qd*4+1], sacc[qd*4+2], sacc[qd*4+3]};
    *(f32x4*)&xch[h][qd][l][0] = v;
  }
  __syncthreads();
  float sv[16];
#pragma unroll
  for (int qd = 0; qd < 4; ++qd) {
    const f32x4 v = *(const f32x4*)&xch[1 - h][qd][l][0];
#pragma unroll
    for (int m = 0; m < 4; ++m) sv[qd*4+m] = sacc[qd*4+m] + v[m];
  }

  const float* mrow = maskg + (size_t)wi * 1024 + il * 32;
  float mx = -1e30f;
#pragma unroll
  for (int r = 0; r < 16; ++r) {
    const int j = (r & 3) + 8 * (r >> 2) + 4 * hi;
    sv[r] += mrow[j];
    mx = fmaxf(mx, sv[r]);
  }
  mx = fmaxf(mx, __shfl_xor(mx, 32));
  float P[16], sum = 0.f;
#pragma unroll
  for (int r = 0; r < 16; ++r) { P[r] = __expf(sv[r] - mx); sum += P[r]; }
  sum += __shfl_xor(sum, 32);
  const float inv = 1.f / sum;

  const float rs_own = st[3];
  const float ms_own = st[2] * st[3];
  float Pp[16], beta = 0.f;
#pragma unroll
  for (int r = 0; r < 16; ++r) {
    const int j = (r & 3) + 8 * (r >> 2) + 4 * hi;
    const float rsj = __shfl(rs_own, j);
    const float msj = __shfl(ms_own, j);
    P[r] *= inv;
    beta -= P[r] * msj;
    Pp[r] = P[r] * rsj;
  }
  beta += __shfl_xor(beta, 32);
  float breg[16];
#pragma unroll
  for (int r = 0; r < 16; ++r) {
    const int ir = (r & 3) + 8 * (r >> 2) + 4 * hi;
    breg[r] = __shfl(beta, ir);
  }

  float Ps[16];
#pragma unroll
  for (int r = 0; r < 16; ++r) Ps[r] = __shfl_xor(Pp[r], 32);
  bf16x8 pa[2];
#pragma unroll
  for (int s = 0; s < 2; ++s) {
#pragma unroll
    for (int m = 0; m < 8; ++m) {
      float v;
      if (m < 4) v = (hi == 0) ? Pp[8*s+m] : Ps[8*s+m+4];
      else       v = (hi == 1) ? Pp[8*s+m] : Ps[8*s+m-4];
      pa[s][m] = (__bf16)v;
    }
  }

  const size_t bbase = (size_t)b * 4096;
#pragma unroll 2
  for (int nt = 0; nt < 8; ++nt) {
    const int c = h * 256 + nt * 32 + il;
    const float* kvc = kvg + bbase * 512 + c;
    bf16x8 pb0, pb1;
#pragma unroll
    for (int e = 0; e < 8; ++e) {
      const int j0 = 8 * hi + e;
      const int r0 = (wbase + j0) & 4095;
      pb0[e] = (__bf16)kvc[(size_t)r0 * 512];
      const int r1 = (wbase + j0 + 16) & 4095;
      pb1[e] = (__bf16)kvc[(size_t)r1 * 512];
    }
    f32x16 x = {};
    x = __builtin_amdgcn_mfma_f32_32x32x16_bf16(pa[0], pb0, x, 0, 0, 0);
    x = __builtin_amdgcn_mfma_f32_32x32x16_bf16(pa[1], pb1, x, 0, 0, 0);

    const int p  = h * 16 + nt * 2 + (il >> 4);
    const int np = (wbase + p) & 4095;
    const size_t orow = (bbase + np) * 512;
    const float w1c = n1w[c], b1c = n1b[c];
    float ov[16], s1 = 0.f, s2 = 0.f;
#pragma unroll
    for (int qd = 0; qd < 4; ++qd) {
      const int q0 = (il & 15) * 32 + 8 * qd + 4 * hi;
      const f32x4 rv = *(const f32x4*)(kvg + orow + q0);
      f32x4 o;
#pragma unroll
      for (int m = 0; m < 4; ++m) {
        const int r = qd * 4 + m;
        const float xv = w1c * (x[r] + breg[r]) + b1c;
        o[m] = xv + rv[m];
        s1 += o[m]; s2 += o[m] * o[m];
        ov[r] = o[m];
      }
      *(f32x4*)(kv_out + orow + q0) = o;
    }
#pragma unroll
    for (int mm = 1; mm <= 8; mm <<= 1) {
      s1 += __shfl_xor(s1, mm); s2 += __shfl_xor(s2, mm);
    }
    s1 += __shfl_xor(s1, 32); s2 += __shfl_xor(s2, 32);
    const float mu2 = s1 * (1.f / 512.f);
    const float rr  = rsqrtf(s2 * (1.f / 512.f) - mu2 * mu2 + 1e-5f);
#pragma unroll
    for (int qd = 0; qd < 4; ++qd) {
      const int q0 = (il & 15) * 32 + 8 * qd + 4 * hi;
      const f32x4 w2v = *(const f32x4*)(n2w + q0);
      const f32x4 b2v = *(const f32x4*)(n2b + q0);
      us4 hh;
#pragma unroll
      for (int m = 0; m < 4; ++m)
        hh[m] = f2bf((ov[qd*4+m] - mu2) * rr * w2v[m] + b2v[m]);
      *(us4*)(hn + orow + q0) = hh;
    }
  }
}

// ---------------------------------------------------------------------------
// GEMM common: 256x256 tile, BK=32, 4-slot LDS ring (128 KiB), depth-3
// counted-vmcnt pipeline, T2 source-side XOR swizzle, T5 setprio, 512 thr.
// Slot layout: A-slots 4x16KB at [0,64K), B-slots 4x16KB at [64K,128K).
// LDS row = 64B (32 bf16); k-chunk position p = g ^ ((row>>1)&3) swizzle.
// Staging: wave wv stages rows wv*16..+15 (chunk=wv) / +128 (chunk=wv+8);
//   lane l -> row c*16+(l>>2), holds global k-chunk (l&3)^((l>>3)&3).
// ds_read: lane off (l&15)*64 + ((l>>4)^((l>>1)&3))*16  (2-way banks, free).
// Pipeline: iter t stages tile t+3 (4 loads/thread-wave), computes tile t,
//   ends with vmcnt(8) [retires tile t+1] + raw barrier. Tails: 8,4,0.
// ---------------------------------------------------------------------------
#define G_ST(K, slot, kt, chunk, pa, pb)                                      \
  do {                                                                        \
    GLDS16((pa) + (size_t)(kt) * 32, smem + (slot) * 16384 + (chunk) * 1024); \
    GLDS16((pb) + (size_t)(kt) * 32,                                          \
           smem + 65536 + (slot) * 16384 + (chunk) * 1024);                   \
  } while (0)

#define G_ITER(K, kt, DOSTAGE, VMTAIL)                                        \
  {                                                                           \
    const int slot_ = (kt) & 3;                                               \
    const int ss_ = ((kt) + 3) & 3;                                           \
    if (DOSTAGE) G_ST(K, ss_, (kt) + 3, wv, pA0, pB0);                        \
    const char* Ab = smem + slot_ * 16384 + wm * 8192 + laneoff;              \
    const char* Bb = smem + 65536 + slot_ * 16384 + wn * 4096 + laneoff;      \
    bf16x8 bf[4], af[4];                                                      \
    _Pragma("unroll") for (int ni = 0; ni < 4; ++ni)                          \
        bf[ni] = *(const bf16x8*)(Bb + ni * 1024);                            \
    _Pragma("unroll") for (int mi = 0; mi < 4; ++mi)                          \
        af[mi] = *(const bf16x8*)(Ab + mi * 1024);                            \
    __builtin_amdgcn_s_setprio(1);                                            \
    _Pragma("unroll") for (int mi = 0; mi < 4; ++mi)                          \
        _Pragma("unroll") for (int ni = 0; ni < 4; ++ni)                      \
            acc[mi][ni] = __builtin_amdgcn_mfma_f32_16x16x32_bf16(            \
                af[mi], bf[ni], acc[mi][ni], 0, 0, 0);                        \
    __builtin_amdgcn_s_setprio(0);                                            \
    BAR();                                                                    \
    if (DOSTAGE) G_ST(K, ss_, (kt) + 3, wv + 8, pA1, pB1);                    \
    _Pragma("unroll") for (int mi = 0; mi < 4; ++mi)                          \
        af[mi] = *(const bf16x8*)(Ab + 4096 + mi * 1024);                     \
    __builtin_amdgcn_s_setprio(1);                                            \
    _Pragma("unroll") for (int mi = 0; mi < 4; ++mi)                          \
        _Pragma("unroll") for (int ni = 0; ni < 4; ++ni)                      \
            acc[mi + 4][ni] = __builtin_amdgcn_mfma_f32_16x16x32_bf16(        \
                af[mi], bf[ni], acc[mi + 4][ni], 0, 0, 0);                    \
    __builtin_amdgcn_s_setprio(0);                                            \
    VMTAIL;                                                                   \
    BAR();                                                                    \
  }

// Kernel 3: Y1 = gelu(hn @ w1b^T + b1)  M=32768 N=2048 K=512, NT=16
__global__ __launch_bounds__(512, 2) void gemm1_kernel(
    const unsigned short* __restrict__ A, const unsigned short* __restrict__ Bw,
    const float* __restrict__ bias, unsigned short* __restrict__ Y) {
  __shared__ __align__(16) char smem[131072];
  const int tid = threadIdx.x;
  const int l   = tid & 63;
  const int wv  = tid >> 6;
  const int wm  = wv >> 2;
  const int wn  = wv & 3;

  // T1: bijective XCD swizzle, nwg=1024 (%8==0)
  const int bid  = blockIdx.x;
  const int swz  = (bid & 7) * 128 + (bid >> 3);
  const int m0   = (swz >> 3) << 8;
  const int n0   = (swz & 7) << 8;

  const int sw = (((l & 3) ^ ((l >> 3) & 3)) << 3);
  const unsigned short* pA0 = A  + (size_t)(m0 + wv * 16 + (l >> 2)) * 512 + sw;
  const unsigned short* pA1 = pA0 + (size_t)128 * 512;
  const unsigned short* pB0 = Bw + (size_t)(n0 + wv * 16 + (l >> 2)) * 512 + sw;
  const unsigned short* pB1 = pB0 + (size_t)128 * 512;
  const int laneoff = ((l & 15) << 6) + (((l >> 4) ^ ((l >> 1) & 3)) << 4);

  f32x4 acc[8][4] = {};

  G_ST(512, 0, 0, wv, pA0, pB0); G_ST(512, 0, 0, wv + 8, pA1, pB1);
  G_ST(512, 1, 1, wv, pA0, pB0); G_ST(512, 1, 1, wv + 8, pA1, pB1);
  G_ST(512, 2, 2, wv, pA0, pB0); G_ST(512, 2, 2, wv + 8, pA1, pB1);
  VMW(8); BAR();

  for (int t = 0; t < 13; ++t) G_ITER(512, t, true, VMW(8));
  G_ITER(512, 13, false, VMW(4));
  G_ITER(512, 14, false, VMW(0));
  G_ITER(512, 15, false, ((void)0));

  // epilogue: bias + exact gelu, swizzled LDS transpose, us8 stores
  float bn[4];
#pragma unroll
  for (int ni = 0; ni < 4; ++ni)
    bn[ni] = bias[n0 + wn * 64 + ni * 16 + (l & 15)];
  char* Ct = smem + wv * 16384;  // [128 rows][128 B]
#pragma unroll
  for (int mi = 0; mi < 8; ++mi)
#pragma unroll
    for (int ni = 0; ni < 4; ++ni)
#pragma unroll
      for (int r = 0; r < 4; ++r) {
        float v = acc[mi][ni][r] + bn[ni];
        v = 0.5f * v * (1.f + erff(v * 0.70710678118654752f));
        const int row = mi * 16 + ((l >> 4) << 2) + r;
        const int cb  = (((ni * 16 + (l & 15)) << 1)) ^ (((row >> 2) & 3) << 5);
        *(unsigned short*)(Ct + row * 128 + cb) = f2bf(v);
      }
  BAR();
  // read at b0 = plain ^ key undoes the write-side XOR (bits 5-6 only, no
  // carry into them from +j<16) -> the 16B hold PLAIN columns (l&7)*8..+7.
  // gcol therefore takes NO second XOR (round-3 bug: double-unswizzle).
#pragma unroll
  for (int it = 0; it < 16; ++it) {
    const int row = it * 8 + (l >> 3);
    const int b0  = ((l & 7) << 4) ^ (((row >> 2) & 3) << 5);
    const us8 v = *(const us8*)(Ct + row * 128 + b0);
    const int grow = m0 + wm * 128 + row;
    const int gcol = n0 + wn * 64 + ((l & 7) << 3);
    *(us8*)(Y + (size_t)grow * 2048 + gcol) = v;
  }
}

// Kernel 4: out = kv_out + (Y1 @ w2b^T + b2)  M=32768 N=512 K=2048, NT=64
__global__ __launch_bounds__(512, 2) void gemm2_kernel(
    const unsigned short* __restrict__ A, const unsigned short* __restrict__ Bw,
    const float* __restrict__ bias, const float* __restrict__ res,
    float* __restrict__ out) {
  __shared__ __align__(16) char smem[131072];
  const int tid = threadIdx.x;
  const int l   = tid & 63;
  const int wv  = tid >> 6;
  const int wm  = wv >> 2;
  const int wn  = wv & 3;

  // T1: bijective XCD swizzle, nwg=256 (%8==0)
  const int bid  = blockIdx.x;
  const int swz  = (bid & 7) * 32 + (bid >> 3);
  const int m0   = (swz >> 1) << 8;
  const int n0   = (swz & 1) << 8;

  const int sw = (((l & 3) ^ ((l >> 3) & 3)) << 3);
  const unsigned short* pA0 = A  + (size_t)(m0 + wv * 16 + (l >> 2)) * 2048 + sw;
  const unsigned short* pA1 = pA0 + (size_t)128 * 2048;
  const unsigned short* pB0 = Bw + (size_t)(n0 + wv * 16 + (l >> 2)) * 2048 + sw;
  const unsigned short* pB1 = pB0 + (size_t)128 * 2048;
  const int laneoff = ((l & 15) << 6) + (((l >> 4) ^ ((l >> 1) & 3)) << 4);

  f32x4 acc[8][4] = {};

  G_ST(2048, 0, 0, wv, pA0, pB0); G_ST(2048, 0, 0, wv + 8, pA1, pB1);
  G_ST(2048, 1, 1, wv, pA0, pB0); G_ST(2048, 1, 1, wv + 8, pA1, pB1);
  G_ST(2048, 2, 2, wv, pA0, pB0); G_ST(2048, 2, 2, wv + 8, pA1, pB1);
  VMW(8); BAR();

  for (int t = 0; t < 61; ++t) G_ITER(2048, t, true, VMW(8));
  G_ITER(2048, 61, false, VMW(4));
  G_ITER(2048, 62, false, VMW(0));
  G_ITER(2048, 63, false, ((void)0));

  // direct epilogue: +bias +residual, scalar f32 stores
#pragma unroll
  for (int ni = 0; ni < 4; ++ni) {
    const int col = n0 + wn * 64 + ni * 16 + (l & 15);
    const float bb = bias[col];
#pragma unroll
    for (int mi = 0; mi < 8; ++mi)
#pragma unroll
      for (int r = 0; r < 4; ++r) {
        const int row = m0 + wm * 128 + mi * 16 + ((l >> 4) << 2) + r;
        const size_t idx = (size_t)row * 512 + col;
        out[idx] = acc[mi][ni][r] + bb + res[idx];
      }
  }
}

// ---------------------------------------------------------------------------
extern "C" void kernel_launch(void* const* d_in, const int* in_sizes, int n_in,
                              void* d_out, int out_size, void* d_ws,
                              size_t ws_size, hipStream_t stream) {
  const float* q   = (const float*)d_in[0];
  const float* kv  = (const float*)d_in[1];
  const float* msk = (const float*)d_in[2];
  const float* n1w = (const float*)d_in[3];
  const float* n1b = (const float*)d_in[4];
  const float* n2w = (const float*)d_in[5];
  const float* n2b = (const float*)d_in[6];
  const float* w1  = (const float*)d_in[7];
  const float* b1  = (const float*)d_in[8];
  const float* w2  = (const float*)d_in[9];
  const float* b2  = (const float*)d_in[10];
  float* out = (float*)d_out;

  char* ws = (char*)d_ws;
  float*          kv_out = (float*)ws;
  unsigned short* hn     = (unsigned short*)(ws + 67108864);
  unsigned short* Y1     = (unsigned short*)(ws + 100663296);
  unsigned short* w1b    = (unsigned short*)(ws + 234881024);
  unsigned short* w2b    = (unsigned short*)(ws + 236978176);
  float*          stats  = (float*)(ws + 239075328);

  hipLaunchKernelGGL(wconv_kernel, dim3(1024), dim3(256), 0, stream,
                     w1, w2, w1b, w2b);
  hipLaunchKernelGGL(stats_kernel, dim3(16384), dim3(256), 0, stream,
                     q, kv, stats);
  hipLaunchKernelGGL(attn2_kernel, dim3(1024), dim3(128), 0, stream,
                     q, kv, msk, n1w, n1b, n2w, n2b, stats, kv_out, hn);
  hipLaunchKernelGGL(gemm1_kernel, dim3(1024), dim3(512), 0, stream,
                     hn, w1b, b1, Y1);
  hipLaunchKernelGGL(gemm2_kernel, dim3(256), dim3(512), 0, stream,
                     Y1, w2b, b2, kv_out, out);
}